// Round 1
// baseline (240.591 us; speedup 1.0000x reference)
//
#include <hip/hip_runtime.h>
#include <math.h>

#define NA 16
#define NS 32
#define NB 100
#define NE 12
#define DD 512
#define NQ (NA*NS)          // 512
#define NC (NA*NE)          // 192
#define OUT_SIM_OFF (NQ*NC) // 98304
#define EPSF 1e-5f
#define DELTAF 0.2f

// ---------------- K1: fused GEMM + max/argmax over Nb ----------------
// grid (3 col-tiles, 512 q-groups), 256 threads.
// Block: rows = 100 (padded 112) of one q-group, cols = 64, Kt = 32.
// Thread (tb,tc) 16x16: 7 rows (b = tb+16i) x 4 cols (c = tc+16j).
constexpr int KT    = 32;
constexpr int AROWS = 112;
constexpr int ASTR  = 36;   // padded stride (floats), 16B-aligned, conflict-free
constexpr int BSTR  = 36;

__global__ __launch_bounds__(256) void k1_gemm_max(
    const float* __restrict__ vis, const float* __restrict__ word,
    const int* __restrict__ ent, float* __restrict__ out)
{
    __shared__ float As[AROWS*ASTR];
    __shared__ float Bs[64*BSTR];
    __shared__ float rval[16][16][4];
    __shared__ int   rind[16][16][4];

    const int t  = threadIdx.x;
    const int tc = t & 15, tb = t >> 4;
    const int c0 = blockIdx.x * 64;
    const int q  = blockIdx.y;
    const float* visq = vis + (size_t)q * NB * DD;

    float acc[7][4];
    #pragma unroll
    for (int i = 0; i < 7; i++)
        #pragma unroll
        for (int j = 0; j < 4; j++) acc[i][j] = 0.f;

    for (int k0 = 0; k0 < DD; k0 += KT) {
        // stage A tile (112 x 32, rows >= 100 zero-filled)
        for (int e2 = t; e2 < 896; e2 += 256) {
            int row = e2 >> 3, k4 = e2 & 7;
            float4 v = make_float4(0.f, 0.f, 0.f, 0.f);
            if (row < NB) v = *(const float4*)(visq + row*DD + k0 + k4*4);
            *(float4*)&As[row*ASTR + k4*4] = v;
        }
        // stage B tile (64 x 32)
        for (int e2 = t; e2 < 512; e2 += 256) {
            int row = e2 >> 3, k4 = e2 & 7;
            float4 v = *(const float4*)(word + (size_t)(c0 + row)*DD + k0 + k4*4);
            *(float4*)&Bs[row*BSTR + k4*4] = v;
        }
        __syncthreads();
        #pragma unroll
        for (int kk = 0; kk < KT; kk += 4) {
            float4 a4[7], b4[4];
            #pragma unroll
            for (int i = 0; i < 7; i++) a4[i] = *(const float4*)&As[(tb + 16*i)*ASTR + kk];
            #pragma unroll
            for (int j = 0; j < 4; j++) b4[j] = *(const float4*)&Bs[(tc + 16*j)*BSTR + kk];
            #pragma unroll
            for (int i = 0; i < 7; i++)
                #pragma unroll
                for (int j = 0; j < 4; j++) {
                    acc[i][j] = fmaf(a4[i].x, b4[j].x, acc[i][j]);
                    acc[i][j] = fmaf(a4[i].y, b4[j].y, acc[i][j]);
                    acc[i][j] = fmaf(a4[i].z, b4[j].z, acc[i][j]);
                    acc[i][j] = fmaf(a4[i].w, b4[j].w, acc[i][j]);
                }
        }
        __syncthreads();
    }

    // epilogue: max/argmax over b (first-occurrence ties -> smallest b)
    #pragma unroll
    for (int j = 0; j < 4; j++) {
        float best = -INFINITY; int besti = 0;
        #pragma unroll
        for (int i = 0; i < 7; i++) {
            int b = tb + 16*i;
            if (b < NB && acc[i][j] > best) { best = acc[i][j]; besti = b; }
        }
        rval[tb][tc][j] = best; rind[tb][tc][j] = besti;
    }
    __syncthreads();
    if (t < 64) {
        int tcc = t >> 2, j = t & 3;
        float best = -INFINITY; int besti = 0;
        #pragma unroll
        for (int tbb = 0; tbb < 16; tbb++) {
            float v = rval[tbb][tcc][j]; int ii = rind[tbb][tcc][j];
            if (v > best || (v == best && ii < besti)) { best = v; besti = ii; }
        }
        int cg = c0 + tcc + 16*j;
        int a2 = cg / NE, e = cg - a2*NE;
        if (e >= ent[a2]) { best = 0.f; besti = 0; }  // masked column: S_ zeroed pre-max
        out[(size_t)q*NC + cg]               = (float)besti;  // D_ind (as float)
        out[OUT_SIM_OFF + (size_t)q*NC + cg] = best;          // D_sim
    }
}

// ---------------- K2: vis path (per (a,e)): simn, vcls gram, vis_loss partials ----
__global__ __launch_bounds__(256) void k2_vis(
    const float* __restrict__ vis, const int* __restrict__ ent,
    const float* __restrict__ out_ro, float* __restrict__ ws)
{
    const int a = blockIdx.x / NE;
    const int e = blockIdx.x - a*NE;
    if (e >= ent[a]) return;  // masked (a,e): contributes nothing (vis_mat zeroed)

    __shared__ float VT[DD*36];   // V transposed [k][s], stride 36
    __shared__ float simv[NS];
    __shared__ int   indv[NS];
    __shared__ float scl[NS];
    __shared__ float wsum[4], wcnt[4];
    const int t = threadIdx.x;

    if (t < NS) {
        int q = a*NS + t;
        simv[t] = out_ro[OUT_SIM_OFF + (size_t)q*NC + a*NE + e];
        indv[t] = (int)out_ro[(size_t)q*NC + a*NE + e];
    }
    __syncthreads();
    if (t < NS) {
        float v = simv[t];
        float mn = v, mx = v;
        #pragma unroll
        for (int off = 16; off >= 1; off >>= 1) {
            mn = fminf(mn, __shfl_xor(mn, off));
            mx = fmaxf(mx, __shfl_xor(mx, off));
        }
        simv[t] = (v - mn) / (mx - mn + EPSF);  // normalized sim score
    }
    __syncthreads();

    // load 32 selected rows (from vis_feats[0..99]) transposed into LDS + sumsq
    const int g = t >> 3, j = t & 7;   // group g (8 threads) owns row s=g
    const float* src = vis + (size_t)indv[g]*DD;
    float ss = 0.f;
    #pragma unroll
    for (int i = 0; i < 16; i++) {
        int k4 = j + 8*i;
        float4 v = *(const float4*)(src + k4*4);
        ss = fmaf(v.x,v.x, fmaf(v.y,v.y, fmaf(v.z,v.z, fmaf(v.w,v.w, ss))));
        int k = k4*4;
        VT[(k+0)*36 + g] = v.x;
        VT[(k+1)*36 + g] = v.y;
        VT[(k+2)*36 + g] = v.z;
        VT[(k+3)*36 + g] = v.w;
    }
    #pragma unroll
    for (int off = 4; off >= 1; off >>= 1) ss += __shfl_xor(ss, off);
    if (j == 0) scl[g] = simv[g] / (sqrtf(ss) + EPSF);   // simn/(||v||+eps)
    __syncthreads();

    // gram: thread (s, tq) computes G[s][4tq..4tq+3]
    const int s = t >> 3, tq = t & 7;
    float g0=0.f, g1=0.f, g2=0.f, g3=0.f;
    for (int k = 0; k < DD; k++) {
        float vs = VT[k*36 + s];
        float4 vt = *(const float4*)&VT[k*36 + tq*4];
        g0 = fmaf(vs, vt.x, g0);
        g1 = fmaf(vs, vt.y, g1);
        g2 = fmaf(vs, vt.z, g2);
        g3 = fmaf(vs, vt.w, g3);
    }
    float lsum = 0.f, lcnt = 0.f;
    float sc_s = scl[s];
    float gv[4] = {g0, g1, g2, g3};
    #pragma unroll
    for (int jj = 0; jj < 4; jj++) {
        int tt = tq*4 + jj;
        if (tt != s) {                       // eye mask
            float val = 1.f - sc_s * scl[tt] * gv[jj];
            lsum += val;
            if (val != 0.f) lcnt += 1.f;     // count_nonzero semantics
        }
    }
    #pragma unroll
    for (int off = 32; off >= 1; off >>= 1) {
        lsum += __shfl_xor(lsum, off);
        lcnt += __shfl_xor(lcnt, off);
    }
    const int wid = t >> 6, lane = t & 63;
    if (lane == 0) { wsum[wid] = lsum; wcnt[wid] = lcnt; }
    __syncthreads();
    if (t == 0) {
        atomicAdd(&ws[0], wsum[0]+wsum[1]+wsum[2]+wsum[3]);
        atomicAdd(&ws[1], wcnt[0]+wcnt[1]+wcnt[2]+wcnt[3]);
    }
}

// ---------------- K3: margin path per a: Smin/Smax over s, Sf -> ws --------------
__global__ __launch_bounds__(256) void k3_margin(
    const float* __restrict__ out_ro, const int* __restrict__ ent,
    float* __restrict__ ws)
{
    const int a = blockIdx.x;
    __shared__ float Ss[NS][NC];
    __shared__ float Smn[NC], Smx[NC];
    const int t = threadIdx.x;
    for (int e2 = t; e2 < NS*NC; e2 += 256) {
        int s = e2 / NC, c = e2 - (e2/NC)*NC;
        Ss[s][c] = out_ro[OUT_SIM_OFF + (size_t)(a*NS + s)*NC + c];
    }
    __syncthreads();
    if (t < NC) {
        float mn = INFINITY, mx = -INFINITY;
        #pragma unroll
        for (int s = 0; s < NS; s++) {
            float v = Ss[s][t];
            mn = fminf(mn, v); mx = fmaxf(mx, v);
        }
        Smn[t] = mn; Smx[t] = mx;
    }
    __syncthreads();
    for (int p = t; p < NS*NA; p += 256) {
        int s = p >> 4, b = p & 15;
        int eb = ent[b];
        float dv = (eb == 0) ? 1.f : (float)eb;
        float sum = 0.f;
        #pragma unroll
        for (int e2 = 0; e2 < NE; e2++) {
            int c = b*NE + e2;
            float S = Ss[s][c];
            float r = (S - Smn[c]) / (Smx[c] - Smn[c] + EPSF);
            sum += S * r;
        }
        ws[2 + a*(NS*NA) + s*NA + b] = sum / dv;   // Sf[a][s][b]
    }
}

// ---------------- K4: final combine -> margin_loss scalar ------------------------
__global__ __launch_bounds__(256) void k4_final(
    const float* __restrict__ ws_ro, float* __restrict__ out)
{
    __shared__ float Sf[NA][NS][NA];
    __shared__ float dg[NA][NS];
    __shared__ float wred[4];
    const int t = threadIdx.x;
    for (int e2 = t; e2 < NA*NS*NA; e2 += 256)
        ((float*)Sf)[e2] = ws_ro[2 + e2];
    __syncthreads();
    for (int p = t; p < NA*NS; p += 256) {
        int aa = p >> 5, s = p & 31;
        dg[aa][s] = Sf[aa][s][aa];
    }
    __syncthreads();
    float fsum = 0.f;
    for (int p = t; p < NA*NS; p += 256) {
        int i = p >> 5, s = p & 31;
        float d = dg[i][s];
        float t1 = 0.f, t2 = 0.f;
        #pragma unroll
        for (int x = 0; x < NA; x++) {
            t1 += fmaxf(Sf[x][s][i] - d + DELTAF, 0.f);  // term1[i,s]*16
            t2 += fmaxf(Sf[i][s][x] - d + DELTAF, 0.f);  // term2[i,s]*16
        }
        fsum += (t1 + t2) * (1.f/16.f);
    }
    #pragma unroll
    for (int off = 32; off >= 1; off >>= 1) fsum += __shfl_xor(fsum, off);
    const int wid = t >> 6, lane = t & 63;
    if (lane == 0) wred[wid] = fsum;
    __syncthreads();
    if (t == 0) {
        float frame_mean = (wred[0]+wred[1]+wred[2]+wred[3]) / 512.f;
        float vis_loss = ws_ro[0] / ws_ro[1];
        out[2*OUT_SIM_OFF] = (frame_mean + 1.0f * vis_loss) * 10.f;
    }
}

extern "C" void kernel_launch(void* const* d_in, const int* in_sizes, int n_in,
                              void* d_out, int out_size, void* d_ws, size_t ws_size,
                              hipStream_t stream)
{
    (void)in_sizes; (void)n_in; (void)out_size; (void)ws_size;
    const float* vis  = (const float*)d_in[0];
    const float* word = (const float*)d_in[1];
    const int*   ent  = (const int*)d_in[2];
    float* out = (float*)d_out;
    float* ws  = (float*)d_ws;

    hipMemsetAsync(d_ws, 0, 2*sizeof(float), stream);  // vis_sum, vis_cnt

    dim3 g1(3, NQ);
    k1_gemm_max<<<g1, 256, 0, stream>>>(vis, word, ent, out);
    k2_vis<<<NA*NE, 256, 0, stream>>>(vis, ent, out, ws);
    k3_margin<<<NA, 256, 0, stream>>>(out, ent, ws);
    k4_final<<<1, 256, 0, stream>>>(ws, out);
}

// Round 2
// 117.083 us; speedup vs baseline: 2.0549x; 2.0549x over previous
//
#include <hip/hip_runtime.h>
#include <math.h>

#define NA 16
#define NS 32
#define NB 100
#define NE 12
#define DD 512
#define NQ (NA*NS)          // 512
#define NC (NA*NE)          // 192
#define OUT_SIM_OFF (NQ*NC) // 98304
#define EPSF 1e-5f
#define DELTAF 0.2f
#define EPS_R 1e-3f
#define FLAG_OFF 1024

typedef __bf16 bf16x8 __attribute__((ext_vector_type(8)));
typedef float f32x4 __attribute__((ext_vector_type(4)));

__device__ __forceinline__ unsigned short f2bf_rne(float x) {
    unsigned int u = __float_as_uint(x);
    unsigned int r = (u + 0x7fffu + ((u >> 16) & 1u)) >> 16;
    return (unsigned short)r;
}

// ---------------- K1: split-bf16 MFMA GEMM + max/argmax + ambiguity flagging ----
// grid 512 (one q-group each), 512 threads = 8 waves (wm = wid>>2 in 0..1, wn = wid&3).
// Block tile: M=128 (rows 100 padded), N=192 (all cols), K chunks of 32.
// LDS holds hi/lo bf16 fragments in MFMA-fragment-major order (linear reads).
__global__ __launch_bounds__(512, 2) void k1_mfma(
    const float* __restrict__ vis, const float* __restrict__ word,
    const int* __restrict__ ent, float* __restrict__ out)
{
    __shared__ unsigned short Ah[2][8*512],  Al[2][8*512];   // 8 mtiles
    __shared__ unsigned short Bh[2][12*512], Bl[2][12*512];  // 12 ntiles
    __shared__ float part_v[2][NC];
    __shared__ int   part_i[2][NC];
    __shared__ float colmax_s[NC];
    __shared__ int   cnt_s[NC];
    __shared__ unsigned char cand_s[NC][3];

    const int t    = threadIdx.x;
    const int lane = t & 63;
    const int wid  = t >> 6;
    const int wm   = wid >> 2;   // 0..1 : rows wm*64 + mi*16
    const int wn   = wid & 3;    // 0..3 : cols wn*48 + ni*16
    const int q    = blockIdx.x;
    const float* visq = vis + (size_t)q * NB * DD;

    f32x4 acc[4][3];
    #pragma unroll
    for (int mi = 0; mi < 4; mi++)
        #pragma unroll
        for (int ni = 0; ni < 3; ni++) acc[mi][ni] = (f32x4)0.f;

    float4 ar[2], br[3];
    // ---- load chunk 0
    {
        const int kbase = 0;
        #pragma unroll
        for (int i = 0; i < 2; i++) {
            int id = t + i*512, row = id >> 3, kq = id & 7;
            ar[i] = make_float4(0.f,0.f,0.f,0.f);
            if (row < NB) ar[i] = *(const float4*)(visq + row*DD + kbase + kq*4);
        }
        #pragma unroll
        for (int i = 0; i < 3; i++) {
            int id = t + i*512, col = id >> 3, kq = id & 7;
            br[i] = *(const float4*)(word + (size_t)col*DD + kbase + kq*4);
        }
    }
    // ---- convert+store chunk 0 into buf 0
    {
        #pragma unroll
        for (int i = 0; i < 2; i++) {
            int id = t + i*512, row = id >> 3, kq = id & 7;
            int off = (row>>4)*512 + ((row&15) + 16*(kq>>1))*8 + (kq&1)*4;
            float4 v = ar[i];
            ushort4 h, l;
            h.x = f2bf_rne(v.x); l.x = f2bf_rne(v.x - __uint_as_float((unsigned)h.x<<16));
            h.y = f2bf_rne(v.y); l.y = f2bf_rne(v.y - __uint_as_float((unsigned)h.y<<16));
            h.z = f2bf_rne(v.z); l.z = f2bf_rne(v.z - __uint_as_float((unsigned)h.z<<16));
            h.w = f2bf_rne(v.w); l.w = f2bf_rne(v.w - __uint_as_float((unsigned)h.w<<16));
            *(ushort4*)&Ah[0][off] = h; *(ushort4*)&Al[0][off] = l;
        }
        #pragma unroll
        for (int i = 0; i < 3; i++) {
            int id = t + i*512, col = id >> 3, kq = id & 7;
            int off = (col>>4)*512 + ((col&15) + 16*(kq>>1))*8 + (kq&1)*4;
            float4 v = br[i];
            ushort4 h, l;
            h.x = f2bf_rne(v.x); l.x = f2bf_rne(v.x - __uint_as_float((unsigned)h.x<<16));
            h.y = f2bf_rne(v.y); l.y = f2bf_rne(v.y - __uint_as_float((unsigned)h.y<<16));
            h.z = f2bf_rne(v.z); l.z = f2bf_rne(v.z - __uint_as_float((unsigned)h.z<<16));
            h.w = f2bf_rne(v.w); l.w = f2bf_rne(v.w - __uint_as_float((unsigned)h.w<<16));
            *(ushort4*)&Bh[0][off] = h; *(ushort4*)&Bl[0][off] = l;
        }
    }
    __syncthreads();

    for (int kc = 0; kc < DD/32; ++kc) {
        const int p = kc & 1;
        const bool have = (kc + 1 < DD/32);
        // prefetch next chunk into regs (in flight during MFMAs)
        if (have) {
            const int kbase = (kc+1)*32;
            #pragma unroll
            for (int i = 0; i < 2; i++) {
                int id = t + i*512, row = id >> 3, kq = id & 7;
                ar[i] = make_float4(0.f,0.f,0.f,0.f);
                if (row < NB) ar[i] = *(const float4*)(visq + row*DD + kbase + kq*4);
            }
            #pragma unroll
            for (int i = 0; i < 3; i++) {
                int id = t + i*512, col = id >> 3, kq = id & 7;
                br[i] = *(const float4*)(word + (size_t)col*DD + kbase + kq*4);
            }
        }
        // compute on buf p
        {
            bf16x8 bhf[3], blf[3];
            #pragma unroll
            for (int ni = 0; ni < 3; ni++) {
                int nt = wn*3 + ni;
                bhf[ni] = *((const bf16x8*)&Bh[p][nt*512 + lane*8]);
                blf[ni] = *((const bf16x8*)&Bl[p][nt*512 + lane*8]);
            }
            #pragma unroll
            for (int mi = 0; mi < 4; mi++) {
                int mt = wm*4 + mi;
                bf16x8 ahf = *((const bf16x8*)&Ah[p][mt*512 + lane*8]);
                bf16x8 alf = *((const bf16x8*)&Al[p][mt*512 + lane*8]);
                #pragma unroll
                for (int ni = 0; ni < 3; ni++) {
                    acc[mi][ni] = __builtin_amdgcn_mfma_f32_16x16x32_bf16(ahf, bhf[ni], acc[mi][ni], 0, 0, 0);
                    acc[mi][ni] = __builtin_amdgcn_mfma_f32_16x16x32_bf16(ahf, blf[ni], acc[mi][ni], 0, 0, 0);
                    acc[mi][ni] = __builtin_amdgcn_mfma_f32_16x16x32_bf16(alf, bhf[ni], acc[mi][ni], 0, 0, 0);
                }
            }
        }
        // store next chunk into buf p^1
        if (have) {
            const int pn = p ^ 1;
            #pragma unroll
            for (int i = 0; i < 2; i++) {
                int id = t + i*512, row = id >> 3, kq = id & 7;
                int off = (row>>4)*512 + ((row&15) + 16*(kq>>1))*8 + (kq&1)*4;
                float4 v = ar[i];
                ushort4 h, l;
                h.x = f2bf_rne(v.x); l.x = f2bf_rne(v.x - __uint_as_float((unsigned)h.x<<16));
                h.y = f2bf_rne(v.y); l.y = f2bf_rne(v.y - __uint_as_float((unsigned)h.y<<16));
                h.z = f2bf_rne(v.z); l.z = f2bf_rne(v.z - __uint_as_float((unsigned)h.z<<16));
                h.w = f2bf_rne(v.w); l.w = f2bf_rne(v.w - __uint_as_float((unsigned)h.w<<16));
                *(ushort4*)&Ah[pn][off] = h; *(ushort4*)&Al[pn][off] = l;
            }
            #pragma unroll
            for (int i = 0; i < 3; i++) {
                int id = t + i*512, col = id >> 3, kq = id & 7;
                int off = (col>>4)*512 + ((col&15) + 16*(kq>>1))*8 + (kq&1)*4;
                float4 v = br[i];
                ushort4 h, l;
                h.x = f2bf_rne(v.x); l.x = f2bf_rne(v.x - __uint_as_float((unsigned)h.x<<16));
                h.y = f2bf_rne(v.y); l.y = f2bf_rne(v.y - __uint_as_float((unsigned)h.y<<16));
                h.z = f2bf_rne(v.z); l.z = f2bf_rne(v.z - __uint_as_float((unsigned)h.z<<16));
                h.w = f2bf_rne(v.w); l.w = f2bf_rne(v.w - __uint_as_float((unsigned)h.w<<16));
                *(ushort4*)&Bh[pn][off] = h; *(ushort4*)&Bl[pn][off] = l;
            }
        }
        __syncthreads();
    }

    // ---- epilogue: per-column max/argmax (first-occurrence) + candidate flag ----
    // C layout 16x16x32: col = lane&15, row = (lane>>4)*4 + reg  [guide m89/m91]
    #pragma unroll
    for (int ni = 0; ni < 3; ni++) {
        float bv = -INFINITY; int bg = 127;
        #pragma unroll
        for (int mi = 0; mi < 4; mi++)
            #pragma unroll
            for (int r = 0; r < 4; r++) {
                int g = wm*64 + mi*16 + ((lane>>4)<<2) + r;
                float v = acc[mi][ni][r];
                if (g < NB && (v > bv || (v == bv && g < bg))) { bv = v; bg = g; }
            }
        #pragma unroll
        for (int off = 16; off <= 32; off <<= 1) {
            float ov = __shfl_xor(bv, off);
            int   og = __shfl_xor(bg, off);
            if (ov > bv || (ov == bv && og < bg)) { bv = ov; bg = og; }
        }
        if (lane < 16) {
            int col = wn*48 + ni*16 + lane;
            part_v[wm][col] = bv; part_i[wm][col] = bg;
        }
    }
    if (t < NC) {
        cnt_s[t] = 0;
        cand_s[t][0] = 0; cand_s[t][1] = 0; cand_s[t][2] = 0;
    }
    __syncthreads();

    float fbv = 0.f; int fbg = 0; bool fmask = true;
    if (t < NC) {
        fbv = part_v[0][t]; fbg = part_i[0][t];
        float v1 = part_v[1][t]; int g1 = part_i[1][t];
        if (v1 > fbv || (v1 == fbv && g1 < fbg)) { fbv = v1; fbg = g1; }
        int a2 = t / NE, e = t - a2*NE;
        fmask = (e >= ent[a2]);
        colmax_s[t] = fmask ? INFINITY : fbv;
    }
    __syncthreads();

    // count/collect rows within EPS_R of column max
    #pragma unroll
    for (int ni = 0; ni < 3; ni++) {
        int col = wn*48 + ni*16 + (lane & 15);
        float cm = colmax_s[col] - EPS_R;
        #pragma unroll
        for (int mi = 0; mi < 4; mi++)
            #pragma unroll
            for (int r = 0; r < 4; r++) {
                int g = wm*64 + mi*16 + ((lane>>4)<<2) + r;
                float v = acc[mi][ni][r];
                if (g < NB && v >= cm) {
                    int s = atomicAdd(&cnt_s[col], 1);
                    if (s < 3) cand_s[col][s] = (unsigned char)g;
                }
            }
    }
    __syncthreads();

    if (t < NC) {
        float indv, simv;
        if (fmask) { indv = 0.f; simv = 0.f; }
        else {
            int cnt = cnt_s[t];
            if (cnt > 1) {
                int cc = cnt < 7 ? cnt : 7;
                int pk = (int)cand_s[t][0] + ((int)cand_s[t][1] << 7)
                       + ((int)cand_s[t][2] << 14) + (cc << 21);
                indv = (float)(fbg + FLAG_OFF);
                simv = (float)pk;
            } else { indv = (float)fbg; simv = fbv; }
        }
        out[(size_t)q*NC + t]               = indv;
        out[OUT_SIM_OFF + (size_t)q*NC + t] = simv;
    }
}

// ---------------- K1b: exact-fp32 rescue of ambiguous columns --------------------
// Sequential fmaf in k order == round-1 kernel == np reference (absmax was 0.0).
__global__ __launch_bounds__(64) void k1_rescue(
    const float* __restrict__ vis, const float* __restrict__ word,
    float* __restrict__ out)
{
    const int q = blockIdx.x, lane = threadIdx.x;
    const float* visq = vis + (size_t)q * NB * DD;
    __shared__ float wcol[DD];

    for (int c = 0; c < NC; ++c) {
        float iv = out[(size_t)q*NC + c];
        if (iv < (float)FLAG_OFF - 0.5f) continue;
        int pk  = (int)out[OUT_SIM_OFF + (size_t)q*NC + c];
        int cnt = pk >> 21;
        for (int i = lane; i < DD/4; i += 64)
            *(float4*)&wcol[i*4] = *(const float4*)(word + (size_t)c*DD + i*4);
        __syncthreads();

        float bv; int bg;
        if (cnt <= 3) {
            int myrow = -1;
            if (lane == 0) myrow = pk & 127;
            else if (lane == 1 && cnt >= 2) myrow = (pk >> 7) & 127;
            else if (lane == 2 && cnt >= 3) myrow = (pk >> 14) & 127;
            float d = -INFINITY;
            if (myrow >= 0) {
                d = 0.f;
                const float* vr = visq + (size_t)myrow * DD;
                for (int m = 0; m < DD/4; ++m) {
                    float4 v = *(const float4*)(vr + m*4);
                    d = fmaf(v.x, wcol[m*4+0], d);
                    d = fmaf(v.y, wcol[m*4+1], d);
                    d = fmaf(v.z, wcol[m*4+2], d);
                    d = fmaf(v.w, wcol[m*4+3], d);
                }
            }
            bv = d; bg = (myrow >= 0) ? myrow : 127;
            #pragma unroll
            for (int off = 1; off <= 2; off <<= 1) {
                float ov = __shfl_xor(bv, off); int og = __shfl_xor(bg, off);
                if (ov > bv || (ov == bv && og < bg)) { bv = ov; bg = og; }
            }
        } else {
            float mbv = -INFINITY; int mbg = 127;
            for (int r = lane; r < NB; r += 64) {
                float d = 0.f;
                const float* vr = visq + (size_t)r * DD;
                for (int m = 0; m < DD/4; ++m) {
                    float4 v = *(const float4*)(vr + m*4);
                    d = fmaf(v.x, wcol[m*4+0], d);
                    d = fmaf(v.y, wcol[m*4+1], d);
                    d = fmaf(v.z, wcol[m*4+2], d);
                    d = fmaf(v.w, wcol[m*4+3], d);
                }
                if (d > mbv || (d == mbv && r < mbg)) { mbv = d; mbg = r; }
            }
            bv = mbv; bg = mbg;
            #pragma unroll
            for (int off = 32; off >= 1; off >>= 1) {
                float ov = __shfl_xor(bv, off); int og = __shfl_xor(bg, off);
                if (ov > bv || (ov == bv && og < bg)) { bv = ov; bg = og; }
            }
        }
        if (lane == 0) {
            out[(size_t)q*NC + c]               = (float)bg;
            out[OUT_SIM_OFF + (size_t)q*NC + c] = bv;
        }
        __syncthreads();
    }
}

// ---------------- K2: vis path (per (a,e)): simn, vcls gram, vis_loss partials ----
__global__ __launch_bounds__(256) void k2_vis(
    const float* __restrict__ vis, const int* __restrict__ ent,
    const float* __restrict__ out_ro, float* __restrict__ ws)
{
    const int a = blockIdx.x / NE;
    const int e = blockIdx.x - a*NE;
    if (e >= ent[a]) return;

    __shared__ float VT[DD*36];
    __shared__ float simv[NS];
    __shared__ int   indv[NS];
    __shared__ float scl[NS];
    __shared__ float wsum[4], wcnt[4];
    const int t = threadIdx.x;

    if (t < NS) {
        int q = a*NS + t;
        simv[t] = out_ro[OUT_SIM_OFF + (size_t)q*NC + a*NE + e];
        indv[t] = (int)out_ro[(size_t)q*NC + a*NE + e];
    }
    __syncthreads();
    if (t < NS) {
        float v = simv[t];
        float mn = v, mx = v;
        #pragma unroll
        for (int off = 16; off >= 1; off >>= 1) {
            mn = fminf(mn, __shfl_xor(mn, off));
            mx = fmaxf(mx, __shfl_xor(mx, off));
        }
        simv[t] = (v - mn) / (mx - mn + EPSF);
    }
    __syncthreads();

    const int g = t >> 3, j = t & 7;
    const float* src = vis + (size_t)indv[g]*DD;
    float ss = 0.f;
    #pragma unroll
    for (int i = 0; i < 16; i++) {
        int k4 = j + 8*i;
        float4 v = *(const float4*)(src + k4*4);
        ss = fmaf(v.x,v.x, fmaf(v.y,v.y, fmaf(v.z,v.z, fmaf(v.w,v.w, ss))));
        int k = k4*4;
        VT[(k+0)*36 + g] = v.x;
        VT[(k+1)*36 + g] = v.y;
        VT[(k+2)*36 + g] = v.z;
        VT[(k+3)*36 + g] = v.w;
    }
    #pragma unroll
    for (int off = 4; off >= 1; off >>= 1) ss += __shfl_xor(ss, off);
    if (j == 0) scl[g] = simv[g] / (sqrtf(ss) + EPSF);
    __syncthreads();

    const int s = t >> 3, tq = t & 7;
    float g0=0.f, g1=0.f, g2=0.f, g3=0.f;
    for (int k = 0; k < DD; k++) {
        float vs = VT[k*36 + s];
        float4 vt = *(const float4*)&VT[k*36 + tq*4];
        g0 = fmaf(vs, vt.x, g0);
        g1 = fmaf(vs, vt.y, g1);
        g2 = fmaf(vs, vt.z, g2);
        g3 = fmaf(vs, vt.w, g3);
    }
    float lsum = 0.f, lcnt = 0.f;
    float sc_s = scl[s];
    float gv[4] = {g0, g1, g2, g3};
    #pragma unroll
    for (int jj = 0; jj < 4; jj++) {
        int tt = tq*4 + jj;
        if (tt != s) {
            float val = 1.f - sc_s * scl[tt] * gv[jj];
            lsum += val;
            if (val != 0.f) lcnt += 1.f;
        }
    }
    #pragma unroll
    for (int off = 32; off >= 1; off >>= 1) {
        lsum += __shfl_xor(lsum, off);
        lcnt += __shfl_xor(lcnt, off);
    }
    const int wid = t >> 6, lane = t & 63;
    if (lane == 0) { wsum[wid] = lsum; wcnt[wid] = lcnt; }
    __syncthreads();
    if (t == 0) {
        atomicAdd(&ws[0], wsum[0]+wsum[1]+wsum[2]+wsum[3]);
        atomicAdd(&ws[1], wcnt[0]+wcnt[1]+wcnt[2]+wcnt[3]);
    }
}

// ---------------- K3: margin path per a ------------------------------------------
__global__ __launch_bounds__(256) void k3_margin(
    const float* __restrict__ out_ro, const int* __restrict__ ent,
    float* __restrict__ ws)
{
    const int a = blockIdx.x;
    __shared__ float Ss[NS][NC];
    __shared__ float Smn[NC], Smx[NC];
    const int t = threadIdx.x;
    for (int e2 = t; e2 < NS*NC; e2 += 256) {
        int s = e2 / NC, c = e2 - (e2/NC)*NC;
        Ss[s][c] = out_ro[OUT_SIM_OFF + (size_t)(a*NS + s)*NC + c];
    }
    __syncthreads();
    if (t < NC) {
        float mn = INFINITY, mx = -INFINITY;
        #pragma unroll
        for (int s = 0; s < NS; s++) {
            float v = Ss[s][t];
            mn = fminf(mn, v); mx = fmaxf(mx, v);
        }
        Smn[t] = mn; Smx[t] = mx;
    }
    __syncthreads();
    for (int p = t; p < NS*NA; p += 256) {
        int s = p >> 4, b = p & 15;
        int eb = ent[b];
        float dv = (eb == 0) ? 1.f : (float)eb;
        float sum = 0.f;
        #pragma unroll
        for (int e2 = 0; e2 < NE; e2++) {
            int c = b*NE + e2;
            float S = Ss[s][c];
            float r = (S - Smn[c]) / (Smx[c] - Smn[c] + EPSF);
            sum += S * r;
        }
        ws[2 + a*(NS*NA) + s*NA + b] = sum / dv;
    }
}

// ---------------- K4: final combine ----------------------------------------------
__global__ __launch_bounds__(256) void k4_final(
    const float* __restrict__ ws_ro, float* __restrict__ out)
{
    __shared__ float Sf[NA][NS][NA];
    __shared__ float dg[NA][NS];
    __shared__ float wred[4];
    const int t = threadIdx.x;
    for (int e2 = t; e2 < NA*NS*NA; e2 += 256)
        ((float*)Sf)[e2] = ws_ro[2 + e2];
    __syncthreads();
    for (int p = t; p < NA*NS; p += 256) {
        int aa = p >> 5, s = p & 31;
        dg[aa][s] = Sf[aa][s][aa];
    }
    __syncthreads();
    float fsum = 0.f;
    for (int p = t; p < NA*NS; p += 256) {
        int i = p >> 5, s = p & 31;
        float d = dg[i][s];
        float t1 = 0.f, t2 = 0.f;
        #pragma unroll
        for (int x = 0; x < NA; x++) {
            t1 += fmaxf(Sf[x][s][i] - d + DELTAF, 0.f);
            t2 += fmaxf(Sf[i][s][x] - d + DELTAF, 0.f);
        }
        fsum += (t1 + t2) * (1.f/16.f);
    }
    #pragma unroll
    for (int off = 32; off >= 1; off >>= 1) fsum += __shfl_xor(fsum, off);
    const int wid = t >> 6, lane = t & 63;
    if (lane == 0) wred[wid] = fsum;
    __syncthreads();
    if (t == 0) {
        float frame_mean = (wred[0]+wred[1]+wred[2]+wred[3]) / 512.f;
        float vis_loss = ws_ro[0] / ws_ro[1];
        out[2*OUT_SIM_OFF] = (frame_mean + 1.0f * vis_loss) * 10.f;
    }
}

extern "C" void kernel_launch(void* const* d_in, const int* in_sizes, int n_in,
                              void* d_out, int out_size, void* d_ws, size_t ws_size,
                              hipStream_t stream)
{
    (void)in_sizes; (void)n_in; (void)out_size; (void)ws_size;
    const float* vis  = (const float*)d_in[0];
    const float* word = (const float*)d_in[1];
    const int*   ent  = (const int*)d_in[2];
    float* out = (float*)d_out;
    float* ws  = (float*)d_ws;

    hipMemsetAsync(d_ws, 0, 2*sizeof(float), stream);

    k1_mfma<<<NQ, 512, 0, stream>>>(vis, word, ent, out);
    k1_rescue<<<NQ, 64, 0, stream>>>(vis, word, out);
    k2_vis<<<NA*NE, 256, 0, stream>>>(vis, ent, out, ws);
    k3_margin<<<NA, 256, 0, stream>>>(out, ent, ws);
    k4_final<<<1, 256, 0, stream>>>(ws, out);
}

// Round 4
// 78.509 us; speedup vs baseline: 3.0645x; 1.4913x over previous
//
#include <hip/hip_runtime.h>
#include <math.h>

#define NA 16
#define NS 32
#define NB 100
#define NE 12
#define DD 512
#define NQ (NA*NS)          // 512
#define NC (NA*NE)          // 192
#define OUT_SIM_OFF (NQ*NC) // 98304
#define EPSF 1e-5f
#define DELTAF 0.2f
#define EPS_R 3e-3f

// ws layout (floats): [0]=vis_sum, [1]=vis_cnt, [2..8193]=Sf, [12288..]=B bf16 frags
#define WS_B_FOFF 12288
// B frag region: [kc=16][nt=12][hl=2][512] shorts = 196608 shorts = 384 KB

typedef __bf16 bf16x8 __attribute__((ext_vector_type(8)));
typedef float f32x4 __attribute__((ext_vector_type(4)));

__device__ __forceinline__ unsigned short f2bf_rne(float x) {
    unsigned int u = __float_as_uint(x);
    unsigned int r = (u + 0x7fffu + ((u >> 16) & 1u)) >> 16;
    return (unsigned short)r;
}
__device__ __forceinline__ void split4(float4 v, ushort4& h, ushort4& l) {
    h.x = f2bf_rne(v.x); l.x = f2bf_rne(v.x - __uint_as_float((unsigned)h.x<<16));
    h.y = f2bf_rne(v.y); l.y = f2bf_rne(v.y - __uint_as_float((unsigned)h.y<<16));
    h.z = f2bf_rne(v.z); l.z = f2bf_rne(v.z - __uint_as_float((unsigned)h.z<<16));
    h.w = f2bf_rne(v.w); l.w = f2bf_rne(v.w - __uint_as_float((unsigned)h.w<<16));
}

// ---------------- K0: pre-convert word -> fragment-major bf16 hi/lo in ws ------
// grid 192 = (kc 0..15) x (nt 0..11), 64 threads. lane l owns frag shorts [8l,8l+8):
// element j of lane l = word[nt*16 + (l&15)][kc*32 + (l>>4)*8 + j]
__global__ __launch_bounds__(64) void k0_conv(
    const float* __restrict__ word, float* __restrict__ ws)
{
    const int kcc = blockIdx.x / 12;
    const int nt  = blockIdx.x - kcc*12;
    const int l   = threadIdx.x;
    if (blockIdx.x == 0 && l < 2) ws[l] = 0.f;   // zero vis_sum/vis_cnt each launch

    const int col = nt*16 + (l & 15);
    const int k   = kcc*32 + (l >> 4)*8;
    const float* src = word + (size_t)col*DD + k;
    float4 v0 = *(const float4*)(src);
    float4 v1 = *(const float4*)(src + 4);
    ushort4 h0, l0, h1, l1;
    split4(v0, h0, l0); split4(v1, h1, l1);
    unsigned short* wsB = (unsigned short*)(ws + WS_B_FOFF);
    unsigned short* base = wsB + ((size_t)kcc*12288) + (nt*2)*512;
    *(ushort4*)&base[l*8]       = h0;  // hi, elems 0..3
    *(ushort4*)&base[l*8 + 4]   = h1;  // hi, elems 4..7
    *(ushort4*)&base[512 + l*8]     = l0;  // lo
    *(ushort4*)&base[512 + l*8 + 4] = l1;
}

// ---------------- K1: split-bf16 MFMA GEMM + max/argmax + fused exact rescue ----
// grid 512 (one q-group), 512 threads = 8 waves; wave (wm = wid>>2, wn = wid&3).
// Tile M=128 x N=192, K chunks of 32. LDS pool 80 KiB: A 2x16KB (reg-staged,
// lane-linear writes), B 2x24KB (global_load_lds DMA from pre-converted ws).
__global__ __launch_bounds__(512, 4) void k1_mfma(
    const float* __restrict__ vis, const float* __restrict__ word,
    const unsigned short* __restrict__ wsB,
    const int* __restrict__ ent, float* __restrict__ out)
{
    __shared__ __align__(16) char pool[81920];
    unsigned short* Abuf = (unsigned short*)pool;            // [2][8 mt][2 hl][512] = 2 x 8192 shorts
    unsigned short* Bbuf = (unsigned short*)(pool + 32768);  // [2][12 nt][2 hl][512] = 2 x 12288 shorts
    // epilogue aliases (valid after final __syncthreads of the K loop):
    float* part_v = (float*)pool;                 // [2][192]
    int*   part_i = (int*)(pool + 1536);          // [2][192]
    float* colmax = (float*)(pool + 3072);        // [192]
    int*   cnts   = (int*)(pool + 3840);          // [192]
    int*   cand   = (int*)(pool + 4608);          // [192] 3 rows packed (row+1)<<8s
    int*   flist  = (int*)(pool + 5376);          // [192]
    int*   nflag  = (int*)(pool + 6144);

    const int t    = threadIdx.x;
    const int lane = t & 63;
    const int wid  = t >> 6;
    const int wm   = wid >> 2;   // 0..1
    const int wn   = wid & 3;    // 0..3
    const int q    = blockIdx.x;
    const float* visq = vis + (size_t)q * NB * DD;

    f32x4 acc[4][3];
    #pragma unroll
    for (int mi = 0; mi < 4; mi++)
        #pragma unroll
        for (int ni = 0; ni < 3; ni++) acc[mi][ni] = (f32x4)0.f;

    // ---- A slot mapping: slot = t + i*512 (i=0,1):
    //  mt = slot>>7, r = (slot>>1)&63, jh = slot&1
    //  global: row = mt*16 + (r&15), k = kb + (r>>4)*8 + jh*4  (float4)
    //  LDS:    shorts A[p][mt][hl][(slot&127)*4 .. +4)  -> byte-linear per wave
    //  (lane l, elem j of frag mt  <->  A[row = mt*16 + (l&15)][k = kb + (l>>4)*8 + j])
    #define A_LOAD(av, i, kb)                                                  \
        {   int slot = t + (i)*512;                                            \
            int r = (slot >> 1) & 63;                                          \
            int row = ((slot >> 7) << 4) + (r & 15);                           \
            av = make_float4(0.f,0.f,0.f,0.f);                                 \
            if (row < NB)                                                      \
                av = *(const float4*)(visq + (size_t)row*DD + (kb) + ((r>>4)<<3) + ((slot&1)<<2)); }
    #define A_STORE(av, i, pn)                                                 \
        {   int slot = t + (i)*512;                                            \
            unsigned short* ap = Abuf + (pn)*8192 + ((slot>>7)<<10) + ((slot&127)<<2); \
            ushort4 h, l; split4(av, h, l);                                    \
            *(ushort4*)&ap[0]   = h;                                           \
            *(ushort4*)&ap[512] = l; }

    // ---- prologue: stage chunk 0
    {
        const unsigned short* bsrc = wsB;            // kc=0
        unsigned short* bdst = Bbuf;                 // buf 0
        #pragma unroll
        for (int i = 0; i < 3; i++)
            __builtin_amdgcn_global_load_lds(
                (const void*)(bsrc + ((size_t)(i*512 + wid*64 + lane))*8),
                (void*)(bdst + (i*512 + wid*64)*8), 16, 0, 0);
        float4 a0, a1;
        A_LOAD(a0, 0, 0); A_LOAD(a1, 1, 0);
        A_STORE(a0, 0, 0); A_STORE(a1, 1, 0);
    }
    __syncthreads();

    for (int kc = 0; kc < 16; ++kc) {
        const int p = kc & 1;
        float4 a0, a1;
        if (kc < 15) {
            const int kb = (kc+1)*32;
            A_LOAD(a0, 0, kb); A_LOAD(a1, 1, kb);           // issue early (T14)
            const unsigned short* bsrc = wsB + (size_t)(kc+1)*12288;
            unsigned short* bdst = Bbuf + (p^1)*12288;
            #pragma unroll
            for (int i = 0; i < 3; i++)
                __builtin_amdgcn_global_load_lds(
                    (const void*)(bsrc + ((size_t)(i*512 + wid*64 + lane))*8),
                    (void*)(bdst + (i*512 + wid*64)*8), 16, 0, 0);
        }
        // ---- MFMA phase on buffer p
        {
            const unsigned short* Bp = Bbuf + p*12288;
            const unsigned short* Ap = Abuf + p*8192;
            bf16x8 bhf[3], blf[3];
            #pragma unroll
            for (int ni = 0; ni < 3; ni++) {
                int nt = wn*3 + ni;
                bhf[ni] = *((const bf16x8*)&Bp[(nt*2)*512 + lane*8]);
                blf[ni] = *((const bf16x8*)&Bp[(nt*2+1)*512 + lane*8]);
            }
            #pragma unroll
            for (int mi = 0; mi < 4; mi++) {
                int mt = wm*4 + mi;
                bf16x8 ahf = *((const bf16x8*)&Ap[mt*1024 + lane*8]);
                bf16x8 alf = *((const bf16x8*)&Ap[mt*1024 + 512 + lane*8]);
                #pragma unroll
                for (int ni = 0; ni < 3; ni++) {
                    acc[mi][ni] = __builtin_amdgcn_mfma_f32_16x16x32_bf16(ahf, bhf[ni], acc[mi][ni], 0, 0, 0);
                    acc[mi][ni] = __builtin_amdgcn_mfma_f32_16x16x32_bf16(ahf, blf[ni], acc[mi][ni], 0, 0, 0);
                    acc[mi][ni] = __builtin_amdgcn_mfma_f32_16x16x32_bf16(alf, bhf[ni], acc[mi][ni], 0, 0, 0);
                }
            }
        }
        if (kc < 15) { A_STORE(a0, 0, (p^1)); A_STORE(a1, 1, (p^1)); }   // convert late
        __syncthreads();   // drains vmcnt (incl. global_load_lds) + lgkm
    }

    // ---- E1: per-wave partial max/argmax; init flag structures ----
    // C frag: col = lane&15, row = (lane>>4)*4 + r
    #pragma unroll
    for (int ni = 0; ni < 3; ni++) {
        float bv = -INFINITY; int bg = 1000;
        #pragma unroll
        for (int mi = 0; mi < 4; mi++)
            #pragma unroll
            for (int r = 0; r < 4; r++) {
                int g = wm*64 + mi*16 + ((lane>>4)<<2) + r;
                float v = acc[mi][ni][r];
                if (g < NB && (v > bv || (v == bv && g < bg))) { bv = v; bg = g; }
            }
        #pragma unroll
        for (int off = 16; off <= 32; off <<= 1) {
            float ov = __shfl_xor(bv, off);
            int   og = __shfl_xor(bg, off);
            if (ov > bv || (ov == bv && og < bg)) { bv = ov; bg = og; }
        }
        if (lane < 16) {
            int col = wn*48 + ni*16 + lane;
            part_v[wm*NC + col] = bv; part_i[wm*NC + col] = bg;
        }
    }
    if (t < NC) { cnts[t] = 0; cand[t] = 0; }
    if (t == 0) *nflag = 0;
    __syncthreads();

    // ---- E2: final per-column reduce + colmax ----
    float fbv = 0.f; int fbg = 0; bool fmask = true;
    if (t < NC) {
        fbv = part_v[t]; fbg = part_i[t];
        float v1 = part_v[NC + t]; int g1 = part_i[NC + t];
        if (v1 > fbv || (v1 == fbv && g1 < fbg)) { fbv = v1; fbg = g1; }
        int a2 = t / NE, e = t - a2*NE;
        fmask = (e >= ent[a2]);
        colmax[t] = fmask ? INFINITY : fbv;
    }
    __syncthreads();

    // ---- E3: collect candidate rows within EPS_R of column max ----
    #pragma unroll
    for (int ni = 0; ni < 3; ni++) {
        int col = wn*48 + ni*16 + (lane & 15);
        float cm = colmax[col] - EPS_R;
        #pragma unroll
        for (int mi = 0; mi < 4; mi++)
            #pragma unroll
            for (int r = 0; r < 4; r++) {
                int g = wm*64 + mi*16 + ((lane>>4)<<2) + r;
                float v = acc[mi][ni][r];
                if (g < NB && v >= cm) {
                    int s = atomicAdd(&cnts[col], 1);
                    if (s < 3) atomicOr(&cand[col], (g + 1) << (8*s));
                }
            }
    }
    __syncthreads();

    // ---- E4: write non-flagged columns; build flagged list ----
    if (t < NC) {
        if (fmask) {
            out[(size_t)q*NC + t] = 0.f;
            out[OUT_SIM_OFF + (size_t)q*NC + t] = 0.f;
        } else if (cnts[t] <= 1) {
            out[(size_t)q*NC + t] = (float)fbg;
            out[OUT_SIM_OFF + (size_t)q*NC + t] = fbv;
        } else {
            int idx = atomicAdd(nflag, 1);
            flist[idx] = t;
        }
    }
    __syncthreads();

    // ---- E5: exact fp32 rescue (sequential fmaf, ascending k == np) ----
    const int nf = *nflag;
    for (int f = wid; f < nf; f += 8) {
        int col = flist[f];
        int cnt = cnts[col];
        float bv; int bg;
        if (cnt <= 3) {
            int cpk = cand[col];
            int myrow = (lane < cnt) ? (((cpk >> (8*lane)) & 255) - 1) : -1;
            float d = -INFINITY;
            if (myrow >= 0) {
                d = 0.f;
                const float* vr = visq + (size_t)myrow*DD;
                const float* wc = word + (size_t)col*DD;
                for (int m = 0; m < DD/4; ++m) {
                    float4 a = *(const float4*)(vr + m*4);
                    float4 b = *(const float4*)(wc + m*4);
                    d = fmaf(a.x, b.x, d); d = fmaf(a.y, b.y, d);
                    d = fmaf(a.z, b.z, d); d = fmaf(a.w, b.w, d);
                }
            }
            bv = d; bg = (myrow >= 0) ? myrow : 1000;
            #pragma unroll
            for (int off = 1; off <= 2; off <<= 1) {
                float ov = __shfl_xor(bv, off); int og = __shfl_xor(bg, off);
                if (ov > bv || (ov == bv && og < bg)) { bv = ov; bg = og; }
            }
        } else {
            float mbv = -INFINITY; int mbg = 1000;
            const float* wc = word + (size_t)col*DD;
            for (int r = lane; r < NB; r += 64) {
                float d = 0.f;
                const float* vr = visq + (size_t)r*DD;
                for (int m = 0; m < DD/4; ++m) {
                    float4 a = *(const float4*)(vr + m*4);
                    float4 b = *(const float4*)(wc + m*4);
                    d = fmaf(a.x, b.x, d); d = fmaf(a.y, b.y, d);
                    d = fmaf(a.z, b.z, d); d = fmaf(a.w, b.w, d);
                }
                if (d > mbv || (d == mbv && r < mbg)) { mbv = d; mbg = r; }
            }
            bv = mbv; bg = mbg;
            #pragma unroll
            for (int off = 32; off >= 1; off >>= 1) {
                float ov = __shfl_xor(bv, off); int og = __shfl_xor(bg, off);
                if (ov > bv || (ov == bv && og < bg)) { bv = ov; bg = og; }
            }
        }
        if (lane == 0) {
            out[(size_t)q*NC + col] = (float)bg;
            out[OUT_SIM_OFF + (size_t)q*NC + col] = bv;
        }
    }
}

// ---------------- K2: vis path (per (a,e)): simn, vcls gram, vis_loss partials ----
__global__ __launch_bounds__(256) void k2_vis(
    const float* __restrict__ vis, const int* __restrict__ ent,
    const float* __restrict__ out_ro, float* __restrict__ ws)
{
    const int a = blockIdx.x / NE;
    const int e = blockIdx.x - a*NE;
    if (e >= ent[a]) return;

    __shared__ float VT[DD*36];
    __shared__ float simv[NS];
    __shared__ int   indv[NS];
    __shared__ float scl[NS];
    __shared__ float wsum[4], wcnt[4];
    const int t = threadIdx.x;

    if (t < NS) {
        int q = a*NS + t;
        simv[t] = out_ro[OUT_SIM_OFF + (size_t)q*NC + a*NE + e];
        indv[t] = (int)out_ro[(size_t)q*NC + a*NE + e];
    }
    __syncthreads();
    if (t < NS) {
        float v = simv[t];
        float mn = v, mx = v;
        #pragma unroll
        for (int off = 16; off >= 1; off >>= 1) {
            mn = fminf(mn, __shfl_xor(mn, off));
            mx = fmaxf(mx, __shfl_xor(mx, off));
        }
        simv[t] = (v - mn) / (mx - mn + EPSF);
    }
    __syncthreads();

    const int g = t >> 3, j = t & 7;
    const float* src = vis + (size_t)indv[g]*DD;
    float ss = 0.f;
    #pragma unroll
    for (int i = 0; i < 16; i++) {
        int k4 = j + 8*i;
        float4 v = *(const float4*)(src + k4*4);
        ss = fmaf(v.x,v.x, fmaf(v.y,v.y, fmaf(v.z,v.z, fmaf(v.w,v.w, ss))));
        int k = k4*4;
        VT[(k+0)*36 + g] = v.x;
        VT[(k+1)*36 + g] = v.y;
        VT[(k+2)*36 + g] = v.z;
        VT[(k+3)*36 + g] = v.w;
    }
    #pragma unroll
    for (int off = 4; off >= 1; off >>= 1) ss += __shfl_xor(ss, off);
    if (j == 0) scl[g] = simv[g] / (sqrtf(ss) + EPSF);
    __syncthreads();

    const int s = t >> 3, tq = t & 7;
    float g0=0.f, g1=0.f, g2=0.f, g3=0.f;
    for (int k = 0; k < DD; k++) {
        float vs = VT[k*36 + s];
        float4 vt = *(const float4*)&VT[k*36 + tq*4];
        g0 = fmaf(vs, vt.x, g0);
        g1 = fmaf(vs, vt.y, g1);
        g2 = fmaf(vs, vt.z, g2);
        g3 = fmaf(vs, vt.w, g3);
    }
    float lsum = 0.f, lcnt = 0.f;
    float sc_s = scl[s];
    float gv[4] = {g0, g1, g2, g3};
    #pragma unroll
    for (int jj = 0; jj < 4; jj++) {
        int tt = tq*4 + jj;
        if (tt != s) {
            float val = 1.f - sc_s * scl[tt] * gv[jj];
            lsum += val;
            if (val != 0.f) lcnt += 1.f;
        }
    }
    #pragma unroll
    for (int off = 32; off >= 1; off >>= 1) {
        lsum += __shfl_xor(lsum, off);
        lcnt += __shfl_xor(lcnt, off);
    }
    const int wid = t >> 6, lane = t & 63;
    if (lane == 0) { wsum[wid] = lsum; wcnt[wid] = lcnt; }
    __syncthreads();
    if (t == 0) {
        atomicAdd(&ws[0], wsum[0]+wsum[1]+wsum[2]+wsum[3]);
        atomicAdd(&ws[1], wcnt[0]+wcnt[1]+wcnt[2]+wcnt[3]);
    }
}

// ---------------- K3: margin path per a ------------------------------------------
__global__ __launch_bounds__(256) void k3_margin(
    const float* __restrict__ out_ro, const int* __restrict__ ent,
    float* __restrict__ ws)
{
    const int a = blockIdx.x;
    __shared__ float Ss[NS][NC];
    __shared__ float Smn[NC], Smx[NC];
    const int t = threadIdx.x;
    for (int e2 = t; e2 < NS*NC; e2 += 256) {
        int s = e2 / NC, c = e2 - (e2/NC)*NC;
        Ss[s][c] = out_ro[OUT_SIM_OFF + (size_t)(a*NS + s)*NC + c];
    }
    __syncthreads();
    if (t < NC) {
        float mn = INFINITY, mx = -INFINITY;
        #pragma unroll
        for (int s = 0; s < NS; s++) {
            float v = Ss[s][t];
            mn = fminf(mn, v); mx = fmaxf(mx, v);
        }
        Smn[t] = mn; Smx[t] = mx;
    }
    __syncthreads();
    for (int p = t; p < NS*NA; p += 256) {
        int s = p >> 4, b = p & 15;
        int eb = ent[b];
        float dv = (eb == 0) ? 1.f : (float)eb;
        float sum = 0.f;
        #pragma unroll
        for (int e2 = 0; e2 < NE; e2++) {
            int c = b*NE + e2;
            float S = Ss[s][c];
            float r = (S - Smn[c]) / (Smx[c] - Smn[c] + EPSF);
            sum += S * r;
        }
        ws[2 + a*(NS*NA) + s*NA + b] = sum / dv;
    }
}

// ---------------- K4: final combine ----------------------------------------------
__global__ __launch_bounds__(256) void k4_final(
    const float* __restrict__ ws_ro, float* __restrict__ out)
{
    __shared__ float Sf[NA][NS][NA];
    __shared__ float dg[NA][NS];
    __shared__ float wred[4];
    const int t = threadIdx.x;
    for (int e2 = t; e2 < NA*NS*NA; e2 += 256)
        ((float*)Sf)[e2] = ws_ro[2 + e2];
    __syncthreads();
    for (int p = t; p < NA*NS; p += 256) {
        int aa = p >> 5, s = p & 31;
        dg[aa][s] = Sf[aa][s][aa];
    }
    __syncthreads();
    float fsum = 0.f;
    for (int p = t; p < NA*NS; p += 256) {
        int i = p >> 5, s = p & 31;
        float d = dg[i][s];
        float t1 = 0.f, t2 = 0.f;
        #pragma unroll
        for (int x = 0; x < NA; x++) {
            t1 += fmaxf(Sf[x][s][i] - d + DELTAF, 0.f);
            t2 += fmaxf(Sf[i][s][x] - d + DELTAF, 0.f);
        }
        fsum += (t1 + t2) * (1.f/16.f);
    }
    #pragma unroll
    for (int off = 32; off >= 1; off >>= 1) fsum += __shfl_xor(fsum, off);
    const int wid = t >> 6, lane = t & 63;
    if (lane == 0) wred[wid] = fsum;
    __syncthreads();
    if (t == 0) {
        float frame_mean = (wred[0]+wred[1]+wred[2]+wred[3]) / 512.f;
        float vis_loss = ws_ro[0] / ws_ro[1];
        out[2*OUT_SIM_OFF] = (frame_mean + 1.0f * vis_loss) * 10.f;
    }
}

extern "C" void kernel_launch(void* const* d_in, const int* in_sizes, int n_in,
                              void* d_out, int out_size, void* d_ws, size_t ws_size,
                              hipStream_t stream)
{
    (void)in_sizes; (void)n_in; (void)out_size; (void)ws_size;
    const float* vis  = (const float*)d_in[0];
    const float* word = (const float*)d_in[1];
    const int*   ent  = (const int*)d_in[2];
    float* out = (float*)d_out;
    float* ws  = (float*)d_ws;
    const unsigned short* wsB = (const unsigned short*)(ws + WS_B_FOFF);

    k0_conv<<<192, 64, 0, stream>>>(word, ws);
    k1_mfma<<<NQ, 512, 0, stream>>>(vis, word, wsB, ent, out);
    k2_vis<<<NA*NE, 256, 0, stream>>>(vis, ent, out, ws);
    k3_margin<<<NA, 256, 0, stream>>>(out, ent, ws);
    k4_final<<<1, 256, 0, stream>>>(ws, out);
}

// Round 5
// 62.687 us; speedup vs baseline: 3.8380x; 1.2524x over previous
//
#include <hip/hip_runtime.h>
#include <math.h>

#define NA 16
#define NS 32
#define NB 100
#define NE 12
#define DD 512
#define NQ (NA*NS)          // 512
#define NC (NA*NE)          // 192
#define OUT_SIM_OFF (NQ*NC) // 98304
#define EPSF 1e-5f
#define DELTAF 0.2f
#define EPS_R 0.15f

// ws layout (floats): [0]=vis_sum, [1]=vis_cnt, [2..8193]=Sf, [12288..]=B fp16 frags
#define WS_B_FOFF 12288
// B frag region: [kc=16][nt=12][512] shorts = 98304 shorts = 192 KB

typedef _Float16 f16x8 __attribute__((ext_vector_type(8)));
typedef float f32x4 __attribute__((ext_vector_type(4)));

// ---------------- K0: pre-convert word -> fragment-major fp16 in ws -------------
// grid 192 = kc*12 + nt, 64 threads. lane l, elem j = word[nt*16+(l&15)][kc*32+(l>>4)*8+j]
__global__ __launch_bounds__(64) void k0_conv(
    const float* __restrict__ word, float* __restrict__ ws)
{
    const int kcc = blockIdx.x / 12;
    const int nt  = blockIdx.x - kcc*12;
    const int l   = threadIdx.x;
    if (blockIdx.x == 0 && l < 2) ws[l] = 0.f;   // zero vis_sum/vis_cnt each launch

    const int col = nt*16 + (l & 15);
    const int k   = kcc*32 + (l >> 4)*8;
    const float* src = word + (size_t)col*DD + k;
    float4 v0 = *(const float4*)(src);
    float4 v1 = *(const float4*)(src + 4);
    f16x8 hv;
    hv[0]=(_Float16)v0.x; hv[1]=(_Float16)v0.y; hv[2]=(_Float16)v0.z; hv[3]=(_Float16)v0.w;
    hv[4]=(_Float16)v1.x; hv[5]=(_Float16)v1.y; hv[6]=(_Float16)v1.z; hv[7]=(_Float16)v1.w;
    unsigned short* wsB = (unsigned short*)(ws + WS_B_FOFF);
    *(f16x8*)&wsB[(size_t)kcc*6144 + nt*512 + l*8] = hv;
}

// ---------------- K1: fp16 MFMA GEMM + max/argmax + fused exact rescue ----------
// grid 512 (one q-group), 512 threads = 8 waves; wave (wm = wid>>2, wn = wid&3).
// Tile M=128 x N=192, K chunks of 32. LDS pool 40 KiB: A 2x8KB (reg-staged fp16,
// lane-linear 16B writes), B 2x12KB (global_load_lds DMA from pre-converted ws).
__global__ __launch_bounds__(512, 4) void k1_mfma(
    const float* __restrict__ vis, const float* __restrict__ word,
    const unsigned short* __restrict__ wsB,
    const int* __restrict__ ent, float* __restrict__ out)
{
    __shared__ __align__(16) char pool[40960];
    unsigned short* Abuf = (unsigned short*)pool;            // [2][8 mt][512] = 2 x 4096 shorts
    unsigned short* Bbuf = (unsigned short*)(pool + 16384);  // [2][12 nt][512] = 2 x 6144 shorts
    // epilogue aliases (valid after final __syncthreads of the K loop):
    float* part_v = (float*)pool;                 // [2][192]
    int*   part_i = (int*)(pool + 1536);          // [2][192]
    float* colmax = (float*)(pool + 3072);        // [192]
    int*   cnts   = (int*)(pool + 3840);          // [192]
    int*   cand   = (int*)(pool + 4608);          // [192] 3 rows packed (row+1)<<8s
    int*   flist  = (int*)(pool + 5376);          // [192]
    int*   nflag  = (int*)(pool + 6144);

    const int t    = threadIdx.x;
    const int lane = t & 63;
    const int wid  = t >> 6;
    const int wm   = wid >> 2;   // 0..1
    const int wn   = wid & 3;    // 0..3
    const int q    = blockIdx.x;
    const float* visq = vis + (size_t)q * NB * DD;

    f32x4 acc[4][3];
    #pragma unroll
    for (int mi = 0; mi < 4; mi++)
        #pragma unroll
        for (int ni = 0; ni < 3; ni++) acc[mi][ni] = (f32x4)0.f;

    // A mapping: thread t = slot: mt = t>>6, l = t&63
    //   global: row = mt*16 + (l&15), k = kb + (l>>4)*8 .. +8   (2 float4)
    //   LDS:    shorts Abuf[p][t*8 .. t*8+8)  -> byte-linear across block
    #define A_LOAD(av0, av1, kb)                                               \
        {   int l_ = t & 63;                                                   \
            int row = ((t >> 6) << 4) + (l_ & 15);                             \
            av0 = make_float4(0.f,0.f,0.f,0.f);                                \
            av1 = make_float4(0.f,0.f,0.f,0.f);                                \
            if (row < NB) {                                                    \
                const float* p_ = visq + (size_t)row*DD + (kb) + ((l_>>4)<<3); \
                av0 = *(const float4*)p_;                                      \
                av1 = *(const float4*)(p_ + 4); } }
    #define A_STORE(av0, av1, pn)                                              \
        {   f16x8 hv;                                                          \
            hv[0]=(_Float16)av0.x; hv[1]=(_Float16)av0.y;                      \
            hv[2]=(_Float16)av0.z; hv[3]=(_Float16)av0.w;                      \
            hv[4]=(_Float16)av1.x; hv[5]=(_Float16)av1.y;                      \
            hv[6]=(_Float16)av1.z; hv[7]=(_Float16)av1.w;                      \
            *(f16x8*)&Abuf[(pn)*4096 + t*8] = hv; }
    // B staging: 768 x 16B transfers per chunk; waves 0-7 do [0,512), waves 0-3 do [512,768)
    #define B_STAGE(kcn, pn)                                                   \
        {   const unsigned short* bsrc = wsB + (size_t)(kcn)*6144;             \
            unsigned short* bdst = Bbuf + (pn)*6144;                           \
            __builtin_amdgcn_global_load_lds(                                  \
                (const void*)(bsrc + ((size_t)(wid*64 + lane))*8),             \
                (void*)(bdst + (wid*64)*8), 16, 0, 0);                         \
            if (wid < 4)                                                       \
                __builtin_amdgcn_global_load_lds(                              \
                    (const void*)(bsrc + ((size_t)(512 + wid*64 + lane))*8),   \
                    (void*)(bdst + (512 + wid*64)*8), 16, 0, 0); }

    // ---- prologue: stage chunk 0 into buf 0
    {
        B_STAGE(0, 0);
        float4 a0, a1;
        A_LOAD(a0, a1, 0);
        A_STORE(a0, a1, 0);
    }
    __syncthreads();

    for (int kc = 0; kc < 16; ++kc) {
        const int p = kc & 1;
        float4 a0, a1;
        if (kc < 15) {
            A_LOAD(a0, a1, (kc+1)*32);   // issue early (T14)
            B_STAGE(kc+1, p^1);
        }
        // ---- MFMA phase on buffer p
        {
            const unsigned short* Bp = Bbuf + p*6144;
            const unsigned short* Ap = Abuf + p*4096;
            f16x8 bf[3];
            #pragma unroll
            for (int ni = 0; ni < 3; ni++)
                bf[ni] = *((const f16x8*)&Bp[(wn*3 + ni)*512 + lane*8]);
            #pragma unroll
            for (int mi = 0; mi < 4; mi++) {
                f16x8 af = *((const f16x8*)&Ap[(wm*4 + mi)*512 + lane*8]);
                #pragma unroll
                for (int ni = 0; ni < 3; ni++)
                    acc[mi][ni] = __builtin_amdgcn_mfma_f32_16x16x32_f16(af, bf[ni], acc[mi][ni], 0, 0, 0);
            }
        }
        if (kc < 15) { A_STORE(a0, a1, (p^1)); }   // convert late
        __syncthreads();   // drains vmcnt (incl. global_load_lds) + lgkm
    }

    // ---- E1: per-wave partial max/argmax; init flag structures ----
    // C frag: col = lane&15, row = (lane>>4)*4 + r
    #pragma unroll
    for (int ni = 0; ni < 3; ni++) {
        float bv = -INFINITY; int bg = 1000;
        #pragma unroll
        for (int mi = 0; mi < 4; mi++)
            #pragma unroll
            for (int r = 0; r < 4; r++) {
                int g = wm*64 + mi*16 + ((lane>>4)<<2) + r;
                float v = acc[mi][ni][r];
                if (g < NB && (v > bv || (v == bv && g < bg))) { bv = v; bg = g; }
            }
        #pragma unroll
        for (int off = 16; off <= 32; off <<= 1) {
            float ov = __shfl_xor(bv, off);
            int   og = __shfl_xor(bg, off);
            if (ov > bv || (ov == bv && og < bg)) { bv = ov; bg = og; }
        }
        if (lane < 16) {
            int col = wn*48 + ni*16 + lane;
            part_v[wm*NC + col] = bv; part_i[wm*NC + col] = bg;
        }
    }
    if (t < NC) { cnts[t] = 0; cand[t] = 0; }
    if (t == 0) *nflag = 0;
    __syncthreads();

    // ---- E2: final per-column reduce + colmax ----
    float fbv = 0.f; int fbg = 0; bool fmask = true;
    if (t < NC) {
        fbv = part_v[t]; fbg = part_i[t];
        float v1 = part_v[NC + t]; int g1 = part_i[NC + t];
        if (v1 > fbv || (v1 == fbv && g1 < fbg)) { fbv = v1; fbg = g1; }
        int a2 = t / NE, e = t - a2*NE;
        fmask = (e >= ent[a2]);
        colmax[t] = fmask ? INFINITY : fbv;
    }
    __syncthreads();

    // ---- E3: collect candidate rows within EPS_R of column max ----
    #pragma unroll
    for (int ni = 0; ni < 3; ni++) {
        int col = wn*48 + ni*16 + (lane & 15);
        float cm = colmax[col] - EPS_R;
        #pragma unroll
        for (int mi = 0; mi < 4; mi++)
            #pragma unroll
            for (int r = 0; r < 4; r++) {
                int g = wm*64 + mi*16 + ((lane>>4)<<2) + r;
                float v = acc[mi][ni][r];
                if (g < NB && v >= cm) {
                    int s = atomicAdd(&cnts[col], 1);
                    if (s < 3) atomicOr(&cand[col], (g + 1) << (8*s));
                }
            }
    }
    __syncthreads();

    // ---- E4: write non-flagged columns; build flagged list ----
    if (t < NC) {
        if (fmask) {
            out[(size_t)q*NC + t] = 0.f;
            out[OUT_SIM_OFF + (size_t)q*NC + t] = 0.f;
        } else if (cnts[t] <= 1) {
            out[(size_t)q*NC + t] = (float)fbg;
            out[OUT_SIM_OFF + (size_t)q*NC + t] = fbv;
        } else {
            int idx = atomicAdd(nflag, 1);
            flist[idx] = t;
        }
    }
    __syncthreads();

    // ---- E5: exact fp32 rescue of flagged columns ----
    const int nf = *nflag;
    for (int f = wid; f < nf; f += 8) {
        int col = flist[f];
        int cnt = cnts[col];
        const float* wc = word + (size_t)col*DD;
        float bv; int bg;
        if (cnt <= 3) {
            // 16 lanes per candidate row, 32 floats each
            int grp = lane >> 4, li = lane & 15;
            int cpk = cand[col];
            int myrow = (grp < cnt) ? (((cpk >> (8*grp)) & 255) - 1) : -1;
            float d = 0.f;
            if (myrow >= 0) {
                const float* vr = visq + (size_t)myrow*DD + li*32;
                const float* wb = wc + li*32;
                #pragma unroll
                for (int m = 0; m < 8; ++m) {
                    float4 a = *(const float4*)(vr + m*4);
                    float4 b = *(const float4*)(wb + m*4);
                    d = fmaf(a.x, b.x, d); d = fmaf(a.y, b.y, d);
                    d = fmaf(a.z, b.z, d); d = fmaf(a.w, b.w, d);
                }
            }
            #pragma unroll
            for (int off = 1; off <= 8; off <<= 1) d += __shfl_xor(d, off);
            float v0 = __shfl(d, 0), v1 = __shfl(d, 16), v2 = __shfl(d, 32);
            int r0 = ( cpk        & 255) - 1;
            int r1 = ((cpk >> 8)  & 255) - 1;
            int r2 = ((cpk >> 16) & 255) - 1;
            bv = v0; bg = r0;
            if (cnt >= 2 && (v1 > bv || (v1 == bv && r1 < bg))) { bv = v1; bg = r1; }
            if (cnt >= 3 && (v2 > bv || (v2 == bv && r2 < bg))) { bv = v2; bg = r2; }
        } else {
            float mbv = -INFINITY; int mbg = 1000;
            for (int r = lane; r < NB; r += 64) {
                float d = 0.f;
                const float* vr = visq + (size_t)r*DD;
                for (int m = 0; m < DD/4; ++m) {
                    float4 a = *(const float4*)(vr + m*4);
                    float4 b = *(const float4*)(wc + m*4);
                    d = fmaf(a.x, b.x, d); d = fmaf(a.y, b.y, d);
                    d = fmaf(a.z, b.z, d); d = fmaf(a.w, b.w, d);
                }
                if (d > mbv || (d == mbv && r < mbg)) { mbv = d; mbg = r; }
            }
            bv = mbv; bg = mbg;
            #pragma unroll
            for (int off = 32; off >= 1; off >>= 1) {
                float ov = __shfl_xor(bv, off); int og = __shfl_xor(bg, off);
                if (ov > bv || (ov == bv && og < bg)) { bv = ov; bg = og; }
            }
        }
        if (lane == 0) {
            out[(size_t)q*NC + col] = (float)bg;
            out[OUT_SIM_OFF + (size_t)q*NC + col] = bv;
        }
    }
}

// ---------------- K2: vis path (per (a,e)): simn, vcls gram, vis_loss partials ----
__global__ __launch_bounds__(256) void k2_vis(
    const float* __restrict__ vis, const int* __restrict__ ent,
    const float* __restrict__ out_ro, float* __restrict__ ws)
{
    const int a = blockIdx.x / NE;
    const int e = blockIdx.x - a*NE;
    if (e >= ent[a]) return;

    __shared__ float VT[DD*36];
    __shared__ float simv[NS];
    __shared__ int   indv[NS];
    __shared__ float scl[NS];
    __shared__ float wsum[4], wcnt[4];
    const int t = threadIdx.x;

    if (t < NS) {
        int q = a*NS + t;
        simv[t] = out_ro[OUT_SIM_OFF + (size_t)q*NC + a*NE + e];
        indv[t] = (int)out_ro[(size_t)q*NC + a*NE + e];
    }
    __syncthreads();
    if (t < NS) {
        float v = simv[t];
        float mn = v, mx = v;
        #pragma unroll
        for (int off = 16; off >= 1; off >>= 1) {
            mn = fminf(mn, __shfl_xor(mn, off));
            mx = fmaxf(mx, __shfl_xor(mx, off));
        }
        simv[t] = (v - mn) / (mx - mn + EPSF);
    }
    __syncthreads();

    const int g = t >> 3, j = t & 7;
    const float* src = vis + (size_t)indv[g]*DD;
    float ss = 0.f;
    #pragma unroll
    for (int i = 0; i < 16; i++) {
        int k4 = j + 8*i;
        float4 v = *(const float4*)(src + k4*4);
        ss = fmaf(v.x,v.x, fmaf(v.y,v.y, fmaf(v.z,v.z, fmaf(v.w,v.w, ss))));
        int k = k4*4;
        VT[(k+0)*36 + g] = v.x;
        VT[(k+1)*36 + g] = v.y;
        VT[(k+2)*36 + g] = v.z;
        VT[(k+3)*36 + g] = v.w;
    }
    #pragma unroll
    for (int off = 4; off >= 1; off >>= 1) ss += __shfl_xor(ss, off);
    if (j == 0) scl[g] = simv[g] / (sqrtf(ss) + EPSF);
    __syncthreads();

    const int s = t >> 3, tq = t & 7;
    float g0=0.f, g1=0.f, g2=0.f, g3=0.f;
    for (int k = 0; k < DD; k++) {
        float vs = VT[k*36 + s];
        float4 vt = *(const float4*)&VT[k*36 + tq*4];
        g0 = fmaf(vs, vt.x, g0);
        g1 = fmaf(vs, vt.y, g1);
        g2 = fmaf(vs, vt.z, g2);
        g3 = fmaf(vs, vt.w, g3);
    }
    float lsum = 0.f, lcnt = 0.f;
    float sc_s = scl[s];
    float gv[4] = {g0, g1, g2, g3};
    #pragma unroll
    for (int jj = 0; jj < 4; jj++) {
        int tt = tq*4 + jj;
        if (tt != s) {
            float val = 1.f - sc_s * scl[tt] * gv[jj];
            lsum += val;
            if (val != 0.f) lcnt += 1.f;
        }
    }
    #pragma unroll
    for (int off = 32; off >= 1; off >>= 1) {
        lsum += __shfl_xor(lsum, off);
        lcnt += __shfl_xor(lcnt, off);
    }
    const int wid = t >> 6, lane = t & 63;
    if (lane == 0) { wsum[wid] = lsum; wcnt[wid] = lcnt; }
    __syncthreads();
    if (t == 0) {
        atomicAdd(&ws[0], wsum[0]+wsum[1]+wsum[2]+wsum[3]);
        atomicAdd(&ws[1], wcnt[0]+wcnt[1]+wcnt[2]+wcnt[3]);
    }
}

// ---------------- K3: margin path per a ------------------------------------------
__global__ __launch_bounds__(256) void k3_margin(
    const float* __restrict__ out_ro, const int* __restrict__ ent,
    float* __restrict__ ws)
{
    const int a = blockIdx.x;
    __shared__ float Ss[NS][NC];
    __shared__ float Smn[NC], Smx[NC];
    const int t = threadIdx.x;
    for (int e2 = t; e2 < NS*NC; e2 += 256) {
        int s = e2 / NC, c = e2 - (e2/NC)*NC;
        Ss[s][c] = out_ro[OUT_SIM_OFF + (size_t)(a*NS + s)*NC + c];
    }
    __syncthreads();
    if (t < NC) {
        float mn = INFINITY, mx = -INFINITY;
        #pragma unroll
        for (int s = 0; s < NS; s++) {
            float v = Ss[s][t];
            mn = fminf(mn, v); mx = fmaxf(mx, v);
        }
        Smn[t] = mn; Smx[t] = mx;
    }
    __syncthreads();
    for (int p = t; p < NS*NA; p += 256) {
        int s = p >> 4, b = p & 15;
        int eb = ent[b];
        float dv = (eb == 0) ? 1.f : (float)eb;
        float sum = 0.f;
        #pragma unroll
        for (int e2 = 0; e2 < NE; e2++) {
            int c = b*NE + e2;
            float S = Ss[s][c];
            float r = (S - Smn[c]) / (Smx[c] - Smn[c] + EPSF);
            sum += S * r;
        }
        ws[2 + a*(NS*NA) + s*NA + b] = sum / dv;
    }
}

// ---------------- K4: final combine ----------------------------------------------
__global__ __launch_bounds__(256) void k4_final(
    const float* __restrict__ ws_ro, float* __restrict__ out)
{
    __shared__ float Sf[NA][NS][NA];
    __shared__ float dg[NA][NS];
    __shared__ float wred[4];
    const int t = threadIdx.x;
    for (int e2 = t; e2 < NA*NS*NA; e2 += 256)
        ((float*)Sf)[e2] = ws_ro[2 + e2];
    __syncthreads();
    for (int p = t; p < NA*NS; p += 256) {
        int aa = p >> 5, s = p & 31;
        dg[aa][s] = Sf[aa][s][aa];
    }
    __syncthreads();
    float fsum = 0.f;
    for (int p = t; p < NA*NS; p += 256) {
        int i = p >> 5, s = p & 31;
        float d = dg[i][s];
        float t1 = 0.f, t2 = 0.f;
        #pragma unroll
        for (int x = 0; x < NA; x++) {
            t1 += fmaxf(Sf[x][s][i] - d + DELTAF, 0.f);
            t2 += fmaxf(Sf[i][s][x] - d + DELTAF, 0.f);
        }
        fsum += (t1 + t2) * (1.f/16.f);
    }
    #pragma unroll
    for (int off = 32; off >= 1; off >>= 1) fsum += __shfl_xor(fsum, off);
    const int wid = t >> 6, lane = t & 63;
    if (lane == 0) wred[wid] = fsum;
    __syncthreads();
    if (t == 0) {
        float frame_mean = (wred[0]+wred[1]+wred[2]+wred[3]) / 512.f;
        float vis_loss = ws_ro[0] / ws_ro[1];
        out[2*OUT_SIM_OFF] = (frame_mean + 1.0f * vis_loss) * 10.f;
    }
}

extern "C" void kernel_launch(void* const* d_in, const int* in_sizes, int n_in,
                              void* d_out, int out_size, void* d_ws, size_t ws_size,
                              hipStream_t stream)
{
    (void)in_sizes; (void)n_in; (void)out_size; (void)ws_size;
    const float* vis  = (const float*)d_in[0];
    const float* word = (const float*)d_in[1];
    const int*   ent  = (const int*)d_in[2];
    float* out = (float*)d_out;
    float* ws  = (float*)d_ws;
    const unsigned short* wsB = (const unsigned short*)(ws + WS_B_FOFF);

    k0_conv<<<192, 64, 0, stream>>>(word, ws);
    k1_mfma<<<NQ, 512, 0, stream>>>(vis, word, wsB, ent, out);
    k2_vis<<<NA*NE, 256, 0, stream>>>(vis, ent, out, ws);
    k3_margin<<<NA, 256, 0, stream>>>(out, ent, ws);
    k4_final<<<1, 256, 0, stream>>>(ws, out);
}